// Round 19
// baseline (421.778 us; speedup 1.0000x reference)
//
#include <hip/hip_runtime.h>
#include <hip/hip_bf16.h>
#include <cstdint>
#include <cstddef>

#define BROWS  16384
#define DDIM   1024
#define HID_N  4096
#define HALF_K 512
#define LDH    8192   // fused H row stride (elements)

typedef __attribute__((ext_vector_type(8))) short s8v;
typedef __attribute__((ext_vector_type(4))) float f4v;
typedef __attribute__((ext_vector_type(2))) float f2v;

__device__ __forceinline__ void gload16(const void* g, void* l) {
  __builtin_amdgcn_global_load_lds(
      (const __attribute__((address_space(1))) unsigned int*)g,
      (__attribute__((address_space(3))) unsigned int*)l, 16, 0, 0);
}
#define BAR()   asm volatile("s_barrier" ::: "memory")
// barrier with LDS-op drain (explicit ds_write -> cross-wave ds_read handoff)
#define BARS()  asm volatile("s_waitcnt lgkmcnt(0)\n\ts_barrier" ::: "memory")
#define SCHED0() __builtin_amdgcn_sched_barrier(0)

template <int N> __device__ __forceinline__ void vmw() {
  if constexpr (N == 0)      asm volatile("s_waitcnt vmcnt(0)" ::: "memory");
  else if constexpr (N == 4) asm volatile("s_waitcnt vmcnt(4)" ::: "memory");
  else if constexpr (N == 8) asm volatile("s_waitcnt vmcnt(8)" ::: "memory");
}

// ---- merged prep: cast_a + 4 weight transposes in ONE dispatch -------------
__device__ __forceinline__ void transpose_body(const float* __restrict__ W,
                                               __hip_bfloat16* __restrict__ WT,
                                               int K, int N, int bx, int by) {
  __shared__ float tile[32][33];
  const int n0 = bx * 32, k0 = by * 32;
  const int tx = threadIdx.x & 31;
  const int ty = threadIdx.x >> 5;
#pragma unroll
  for (int i = 0; i < 32; i += 8)
    tile[ty + i][tx] = W[(size_t)(k0 + ty + i) * N + n0 + tx];
  __syncthreads();
#pragma unroll
  for (int i = 0; i < 32; i += 8)
    WT[(size_t)(n0 + ty + i) * K + k0 + tx] = __float2bfloat16(tile[tx][ty + i]);
}

__global__ __launch_bounds__(256) void prep_kernel(const float* __restrict__ z,
                                                   __hip_bfloat16* __restrict__ a16,
                                                   const float* __restrict__ W1s,
                                                   const float* __restrict__ W1t,
                                                   const float* __restrict__ W2s,
                                                   const float* __restrict__ W2t,
                                                   __hip_bfloat16* __restrict__ w1T,
                                                   __hip_bfloat16* __restrict__ w2sT,
                                                   __hip_bfloat16* __restrict__ w2tT) {
  const int b = blockIdx.x;
  if (b < 4096) {
    const int idx = b * 256 + threadIdx.x;
    const int m  = idx >> 6;
    const int kb = idx & 63;
    const float4* zp = (const float4*)(z + (size_t)m * DDIM + (size_t)kb * 16);
    alignas(16) __hip_bfloat16 t[8];
#pragma unroll
    for (int i = 0; i < 4; ++i) {
      float4 v = zp[i];
      t[2 * i]     = __float2bfloat16(v.x);
      t[2 * i + 1] = __float2bfloat16(v.z);
    }
    *(s8v*)(a16 + (size_t)m * HALF_K + kb * 8) = *(const s8v*)t;
  } else if (b < 6144) {
    const int v = b - 4096;
    transpose_body(W1s, w1T, HALF_K, HID_N, v & 127, v >> 7);
  } else if (b < 8192) {
    const int v = b - 6144;
    transpose_body(W1t, w1T + (size_t)HID_N * HALF_K, HALF_K, HID_N, v & 127, v >> 7);
  } else if (b < 10240) {
    const int v = b - 8192;
    transpose_body(W2s, w2sT, HID_N, HALF_K, v & 15, v >> 4);
  } else {
    const int v = b - 10240;
    transpose_body(W2t, w2tT, HID_N, HALF_K, v & 15, v >> 4);
  }
}

// ---- G1: [SUB x 512] @ [8192 x 512]^T -> H bf16 (relu, bias b1s|b1t) -------
// 256x256 tile, 8 waves, 4-phase, counted vmcnt(4)/tile; one-pass LDS-bounce
// epilogue, cached H stores. Sub-dispatched (4096 rows).
__global__ __launch_bounds__(512, 2)
void gemm1_kernel(const __hip_bfloat16* __restrict__ A,
                  const __hip_bfloat16* __restrict__ BT,
                  const float* __restrict__ b1s, const float* __restrict__ b1t,
                  __hip_bfloat16* __restrict__ Hout) {
  __shared__ alignas(16) char smem[131072];   // 2 x (A 32KB + B 32KB)
  constexpr int NT = HALF_K / 64;             // 8

  const int nwg = gridDim.x;
  const int orig = blockIdx.x;
  const int vid = (orig & 7) * (nwg >> 3) + (orig >> 3);  // XCD-chunked
  const int bx = vid >> 5, by = vid & 31;
  const int m0 = bx * 256, n0 = by * 256;

  const int tid = threadIdx.x;
  const int trow = tid >> 3;
  const int scol = ((tid & 7) * 16) ^ ((trow & 7) << 4);

  const int lane = tid & 63, wid = tid >> 6;
  const int wr = wid >> 2, wc = wid & 3;
  const int lr = lane & 15, lk = lane >> 4;
  const int xo = (lr & 7) << 4;

  int aoff[4][2], boff[2][2];
#pragma unroll
  for (int j = 0; j < 4; ++j)
#pragma unroll
    for (int kk = 0; kk < 2; ++kk)
      aoff[j][kk] = (j * 32 + wr * 16 + lr) * 128 + ((kk * 64 + lk * 16) ^ xo);
#pragma unroll
  for (int nn = 0; nn < 2; ++nn)
#pragma unroll
    for (int kk = 0; kk < 2; ++kk)
      boff[nn][kk] = (nn * 64 + wc * 16 + lr) * 128 + ((kk * 64 + lk * 16) ^ xo);

  f4v acc[8][4] = {};

  auto stage_A = [&](int h, int T) {
#pragma unroll
    for (int l = 0; l < 2; ++l)
      gload16((const char*)A + (size_t)(m0 + h * 128 + l * 64 + trow) * (HALF_K * 2) + (size_t)T * 128 + scol,
              smem + (T & 1) * 65536 + h * 16384 + l * 8192 + tid * 16);
  };
  auto stage_B = [&](int h, int T) {
#pragma unroll
    for (int l = 0; l < 2; ++l)
      gload16((const char*)BT + (size_t)(n0 + h * 128 + l * 64 + trow) * (HALF_K * 2) + (size_t)T * 128 + scol,
              smem + (T & 1) * 65536 + 32768 + h * 16384 + l * 8192 + tid * 16);
  };

  // prologue: tile0 fully + A0/B0 of tile1 (12 gloads); vmcnt(4) -> tile0 done
  stage_A(0, 0); stage_B(0, 0); stage_A(1, 0); stage_B(1, 0);
  stage_A(0, 1); stage_B(0, 1);
  vmw<4>();
  BAR();

  for (int T = 0; T < NT; ++T) {
    const char* bufp = smem + (T & 1) * 65536;
    s8v af[4][2], b0r[2][2], b1r[2][2];

    // q0: read A0 + B0; stage B1(T+1); MFMA acc[0..3][0..1]
#pragma unroll
    for (int j = 0; j < 4; ++j) {
      af[j][0] = *(const s8v*)(bufp + aoff[j][0]);
      af[j][1] = *(const s8v*)(bufp + aoff[j][1]);
    }
#pragma unroll
    for (int nn = 0; nn < 2; ++nn) {
      b0r[nn][0] = *(const s8v*)(bufp + 32768 + boff[nn][0]);
      b0r[nn][1] = *(const s8v*)(bufp + 32768 + boff[nn][1]);
    }
    if (T + 1 < NT) stage_B(1, T + 1);
    BAR(); SCHED0();
    __builtin_amdgcn_s_setprio(1);
#pragma unroll
    for (int j = 0; j < 4; ++j)
#pragma unroll
      for (int nn = 0; nn < 2; ++nn)
#pragma unroll
        for (int kk = 0; kk < 2; ++kk)
          acc[j][nn] = __builtin_amdgcn_mfma_f32_16x16x32_bf16(af[j][kk], b0r[nn][kk], acc[j][nn], 0, 0, 0);
    __builtin_amdgcn_s_setprio(0);
    BAR();

    // q1: read B1; stage A1(T+1); MFMA acc[0..3][2..3]
#pragma unroll
    for (int nn = 0; nn < 2; ++nn) {
      b1r[nn][0] = *(const s8v*)(bufp + 49152 + boff[nn][0]);
      b1r[nn][1] = *(const s8v*)(bufp + 49152 + boff[nn][1]);
    }
    if (T + 1 < NT) stage_A(1, T + 1);
    BAR(); SCHED0();
    __builtin_amdgcn_s_setprio(1);
#pragma unroll
    for (int j = 0; j < 4; ++j)
#pragma unroll
      for (int nn = 0; nn < 2; ++nn)
#pragma unroll
        for (int kk = 0; kk < 2; ++kk)
          acc[j][2 + nn] = __builtin_amdgcn_mfma_f32_16x16x32_bf16(af[j][kk], b1r[nn][kk], acc[j][2 + nn], 0, 0, 0);
    __builtin_amdgcn_s_setprio(0);
    BAR();

    // q2: read A1 (overwrite af); stage A0(T+2); MFMA acc[4..7][0..1] (B0 regs)
#pragma unroll
    for (int j = 0; j < 4; ++j) {
      af[j][0] = *(const s8v*)(bufp + 16384 + aoff[j][0]);
      af[j][1] = *(const s8v*)(bufp + 16384 + aoff[j][1]);
    }
    if (T + 2 < NT) stage_A(0, T + 2);
    BAR(); SCHED0();
    __builtin_amdgcn_s_setprio(1);
#pragma unroll
    for (int j = 0; j < 4; ++j)
#pragma unroll
      for (int nn = 0; nn < 2; ++nn)
#pragma unroll
        for (int kk = 0; kk < 2; ++kk)
          acc[4 + j][nn] = __builtin_amdgcn_mfma_f32_16x16x32_bf16(af[j][kk], b0r[nn][kk], acc[4 + j][nn], 0, 0, 0);
    __builtin_amdgcn_s_setprio(0);
    BAR();

    // q3: no reads; stage B0(T+2); MFMA acc[4..7][2..3] (B1 regs); vmcnt
    if (T + 2 < NT) stage_B(0, T + 2);
    SCHED0();
    __builtin_amdgcn_s_setprio(1);
#pragma unroll
    for (int j = 0; j < 4; ++j)
#pragma unroll
      for (int nn = 0; nn < 2; ++nn)
#pragma unroll
        for (int kk = 0; kk < 2; ++kk)
          acc[4 + j][2 + nn] = __builtin_amdgcn_mfma_f32_16x16x32_bf16(af[j][kk], b1r[nn][kk], acc[4 + j][2 + nn], 0, 0, 0);
    __builtin_amdgcn_s_setprio(0);
    if (T + 2 >= NT) vmw<0>(); else vmw<4>();
    BAR();
  }

  // ---- one-pass epilogue: full 256x256 bf16 image in LDS (128 KB), 2 bars.
  const float* bp = (n0 < HID_N) ? b1s : b1t;
  const int cb0 = n0 & (HID_N - 1);
  float bv[4];
#pragma unroll
  for (int ni = 0; ni < 4; ++ni) bv[ni] = bp[cb0 + ni * 64 + wc * 16 + lr];

#pragma unroll
  for (int mi = 0; mi < 8; ++mi) {
#pragma unroll
    for (int ni = 0; ni < 4; ++ni) {
      const int cb = (ni * 64 + wc * 16 + lr) * 2;
#pragma unroll
      for (int r = 0; r < 4; ++r) {
        const int row = mi * 32 + wr * 16 + lk * 4 + r;
        const int swz = ((row & 7) << 4) ^ (((row >> 3) & 1) << 8);
        float v = fmaxf(acc[mi][ni][r] + bv[ni], 0.0f);
        *(__hip_bfloat16*)(smem + row * 512 + (cb ^ swz)) = __float2bfloat16(v);
      }
    }
  }
  BARS();   // all ds_writes visible before cross-wave readback
#pragma unroll
  for (int i = 0; i < 16; ++i) {
    const int bo = tid * 16 + i * 8192;
    const int row = bo >> 9, cb = bo & 511;
    const int swz = ((row & 7) << 4) ^ (((row >> 3) & 1) << 8);
    s8v v = *(const s8v*)(smem + row * 512 + (cb ^ swz));
    *(s8v*)((char*)Hout + ((size_t)(m0 + row) * LDH + n0) * 2 + cb) = v;   // cached
  }
}

// ---- G2 v5: 2 blocks/CU. Block 128 rows x 64 cols, BOTH streams, 256 thr
// (4 waves: ws=stream, wm=row-half; wave = 64x64 of one stream). BK=32,
// 2 x 24KB buffers (48KB LDS -> 2 blocks/CU), grid 512 = 2/CU. Cross-block
// overlap hides the per-tile vmcnt(0)+barrier convoy. Epilogue: s-waves
// park s in slds[128][68] f32, t-waves fuse zout (nt) + logdet partials.
__global__ __launch_bounds__(256, 2)
void gemm2_kernel(const __hip_bfloat16* __restrict__ H,
                  const __hip_bfloat16* __restrict__ BsT,
                  const __hip_bfloat16* __restrict__ BtT,
                  const float* __restrict__ b2s, const float* __restrict__ b2t,
                  const float* __restrict__ zin, float* __restrict__ zout,
                  float* __restrict__ gpart) {
  __shared__ alignas(16) char smem[49152];    // 2 x 24KB; epilogue 34.8KB
  constexpr int NT = HID_N / 32;              // 128

  const int nwg = gridDim.x;
  const int orig = blockIdx.x;
  const int vid = (orig & 7) * (nwg >> 3) + (orig >> 3);
  const int rb = vid >> 3, by = vid & 7;
  const int m0 = rb * 128, n0c = by * 64;

  const int tid = threadIdx.x;
  const int trow = tid >> 2;                               // 0..63
  const int scol = (((tid & 3) ^ ((tid >> 3) & 3)) << 4);  // pre-swizzled src col

  const int lane = tid & 63, wid = tid >> 6;               // wid 0..3
  const int ws = wid & 1, wm = wid >> 1;                   // stream, row-half
  const int lr = lane & 15, lk = lane >> 4;
  const int xo2 = ((lr >> 1) & 3) << 4;

  const int aBase = ws ? 8192 : 0;         // As | At (8KB each: 128 rows x 64B)
  const int bBase = ws ? 20480 : 16384;    // Bs | Bt (4KB each: 64 rows x 64B)
  int aoff[4], boff[4];
#pragma unroll
  for (int f = 0; f < 4; ++f) {
    aoff[f] = aBase + (wm * 64 + f * 16 + lr) * 64 + ((lk * 16) ^ xo2);
    boff[f] = bBase + (f * 16 + lr) * 64 + ((lk * 16) ^ xo2);
  }

  f4v acc[4][4] = {};

  auto stage = [&](int T) {
    char* dst = smem + (T & 1) * 24576;
    const size_t tcol = (size_t)T * 64 + scol;
#pragma unroll
    for (int l = 0; l < 2; ++l) {  // As rows l*64+trow
      gload16((const char*)H + (size_t)(m0 + l * 64 + trow) * (LDH * 2) + tcol,
              dst + l * 4096 + tid * 16);
      gload16((const char*)H + (size_t)(m0 + l * 64 + trow) * (LDH * 2) + 8192 + tcol,
              dst + 8192 + l * 4096 + tid * 16);
    }
    gload16((const char*)BsT + (size_t)(n0c + trow) * (HID_N * 2) + tcol,
            dst + 16384 + tid * 16);
    gload16((const char*)BtT + (size_t)(n0c + trow) * (HID_N * 2) + tcol,
            dst + 20480 + tid * 16);
  };

  stage(0);
  vmw<0>();
  BAR();

  for (int T = 0; T < NT; ++T) {
    const char* bufp = smem + (T & 1) * 24576;
    s8v af[4], bf[4];
#pragma unroll
    for (int f = 0; f < 4; ++f) af[f] = *(const s8v*)(bufp + aoff[f]);
#pragma unroll
    for (int f = 0; f < 4; ++f) bf[f] = *(const s8v*)(bufp + boff[f]);
    if (T + 1 < NT) stage(T + 1);   // other buffer: readers done at T-1's bar
    __builtin_amdgcn_s_setprio(1);
#pragma unroll
    for (int fm = 0; fm < 4; ++fm)
#pragma unroll
      for (int fn = 0; fn < 4; ++fn)
        acc[fm][fn] = __builtin_amdgcn_mfma_f32_16x16x32_bf16(af[fm], bf[fn], acc[fm][fn], 0, 0, 0);
    __builtin_amdgcn_s_setprio(0);
    if (T + 1 < NT) vmw<0>();
    BAR();
  }

  // ---- epilogue: s-waves park s+bias in slds[128][68] f32; t-waves read s,
  // fuse zout (nt) + logdet partials -> gpart[row][8].
  const float* bp2 = ws ? b2t : b2s;
  float bv[4];
#pragma unroll
  for (int fn = 0; fn < 4; ++fn) bv[fn] = bp2[n0c + fn * 16 + lr];

  float* slds = (float*)smem;   // [128][68] f32 = 34816 B
  if (ws == 0) {
#pragma unroll
    for (int fm = 0; fm < 4; ++fm)
#pragma unroll
      for (int fn = 0; fn < 4; ++fn)
#pragma unroll
        for (int r = 0; r < 4; ++r) {
          const int row = wm * 64 + fm * 16 + lk * 4 + r;
          slds[row * 68 + fn * 16 + lr] = acc[fm][fn][r] + bv[fn];
        }
  }
  BARS();
  if (ws == 1) {
    float pl[4][4] = {};
#pragma unroll
    for (int fm = 0; fm < 4; ++fm) {
#pragma unroll
      for (int fn = 0; fn < 4; ++fn) {
#pragma unroll
        for (int r = 0; r < 4; ++r) {
          const int row = wm * 64 + fm * 16 + lk * 4 + r;
          const int rr = m0 + row;
          const int cg = n0c + fn * 16 + lr;
          const float sv = slds[row * 68 + fn * 16 + lr];
          const float tv = acc[fm][fn][r] + bv[fn];
          pl[fm][r] += sv;
          const size_t base = (size_t)rr * DDIM + 2 * (size_t)cg;
          float2 zv = *(const float2*)(zin + base);
          f2v o;
          o.x = zv.x;
          o.y = zv.y * __expf(sv) + tv;
          __builtin_nontemporal_store(o, (f2v*)(zout + base));
        }
      }
    }
    // reduce over the 16 lr-lanes (rows depend only on lk)
#pragma unroll
    for (int m = 1; m < 16; m <<= 1)
#pragma unroll
      for (int fm = 0; fm < 4; ++fm)
#pragma unroll
        for (int r = 0; r < 4; ++r)
          pl[fm][r] += __shfl_xor(pl[fm][r], m, 64);
    if (lr == 0) {
#pragma unroll
      for (int fm = 0; fm < 4; ++fm)
#pragma unroll
        for (int r = 0; r < 4; ++r) {
          const int rr = m0 + wm * 64 + fm * 16 + lk * 4 + r;
          gpart[(size_t)rr * 8 + by] = pl[fm][r];
        }
    }
  }
}

// ---- ld[row] = sum of 8 partials (fixed order) -----------------------------
__global__ __launch_bounds__(256) void ld_reduce_kernel(const float* __restrict__ gpart,
                                                        float* __restrict__ ld) {
  const int r = blockIdx.x * 256 + threadIdx.x;
  const float4* g = (const float4*)(gpart + (size_t)r * 8);
  float4 v0 = g[0], v1 = g[1];
  ld[r] = ((v0.x + v0.y) + (v0.z + v0.w)) + ((v1.x + v1.y) + (v1.z + v1.w));
}

extern "C" void kernel_launch(void* const* d_in, const int* in_sizes, int n_in,
                              void* d_out, int out_size, void* d_ws, size_t ws_size,
                              hipStream_t stream) {
  const float* z   = (const float*)d_in[0];
  const float* W1s = (const float*)d_in[1];
  const float* b1s = (const float*)d_in[2];
  const float* W2s = (const float*)d_in[3];
  const float* b2s = (const float*)d_in[4];
  const float* W1t = (const float*)d_in[5];
  const float* b1t = (const float*)d_in[6];
  const float* W2t = (const float*)d_in[7];
  const float* b2t = (const float*)d_in[8];
  float* zout = (float*)d_out;
  float* ld   = zout + (size_t)BROWS * DDIM;

  char* ws = (char*)d_ws;
  __hip_bfloat16* a16    = (__hip_bfloat16*)ws;                    // 16 MB
  __hip_bfloat16* w1catT = (__hip_bfloat16*)(ws + 16777216);       // 8 MB
  __hip_bfloat16* w2sT   = (__hip_bfloat16*)(ws + 25165824);       // 4 MB
  __hip_bfloat16* w2tT   = (__hip_bfloat16*)(ws + 29360128);       // 4 MB
  float*          gpart  = (float*)(ws + 33554432);                // 512 KB
  char*           hbase  = ws + 34078720;

  // CH=8192 (gemm2 grid 512 = 2 blocks/CU); fall back if ws is small.
  int CH = 2048;
  for (int c = 8192; c >= 2048; c >>= 1) {
    if (34078720ull + (size_t)c * 16384ull <= ws_size) { CH = c; break; }
  }
  __hip_bfloat16* H = (__hip_bfloat16*)hbase;   // CH x 8192 bf16

  // single merged prep dispatch (cast_a + 4 transposes)
  prep_kernel<<<12288, 256, 0, stream>>>(z, a16, W1s, W1t, W2s, W2t,
                                         w1catT, w2sT, w2tT);

  const int SUB = (CH >= 4096) ? 4096 : CH;   // gemm1 sub-dispatch rows
  for (int mb = 0; mb < BROWS; mb += CH) {
    for (int sub = 0; sub < CH; sub += SUB) {
      gemm1_kernel<<<(SUB / 256) * 32, 512, 0, stream>>>(
          a16 + (size_t)(mb + sub) * HALF_K, w1catT, b1s, b1t,
          H + (size_t)sub * LDH);
    }
    gemm2_kernel<<<(CH / 128) * 8, 256, 0, stream>>>(
        H, w2sT, w2tT, b2s, b2t,
        z + (size_t)mb * DDIM, zout + (size_t)mb * DDIM, gpart + (size_t)mb * 8);
  }
  ld_reduce_kernel<<<BROWS / 256, 256, 0, stream>>>(gpart, ld);
}

// Round 20
// 358.455 us; speedup vs baseline: 1.1767x; 1.1767x over previous
//
#include <hip/hip_runtime.h>
#include <hip/hip_bf16.h>
#include <cstdint>
#include <cstddef>

#define BROWS  16384
#define DDIM   1024
#define HID_N  4096
#define HALF_K 512
#define LDH    8192   // fused H row stride (elements)

typedef __attribute__((ext_vector_type(8))) short s8v;
typedef __attribute__((ext_vector_type(4))) float f4v;
typedef __attribute__((ext_vector_type(2))) float f2v;

__device__ __forceinline__ void gload16(const void* g, void* l) {
  __builtin_amdgcn_global_load_lds(
      (const __attribute__((address_space(1))) unsigned int*)g,
      (__attribute__((address_space(3))) unsigned int*)l, 16, 0, 0);
}
#define BAR()   asm volatile("s_barrier" ::: "memory")
// barrier with LDS-op drain (explicit ds_write -> cross-wave ds_read handoff)
#define BARS()  asm volatile("s_waitcnt lgkmcnt(0)\n\ts_barrier" ::: "memory")
#define SCHED0() __builtin_amdgcn_sched_barrier(0)

template <int N> __device__ __forceinline__ void vmw() {
  if constexpr (N == 0)      asm volatile("s_waitcnt vmcnt(0)" ::: "memory");
  else if constexpr (N == 4) asm volatile("s_waitcnt vmcnt(4)" ::: "memory");
  else if constexpr (N == 8) asm volatile("s_waitcnt vmcnt(8)" ::: "memory");
}

// ---- merged prep: cast_a + 4 weight transposes in ONE dispatch -------------
__device__ __forceinline__ void transpose_body(const float* __restrict__ W,
                                               __hip_bfloat16* __restrict__ WT,
                                               int K, int N, int bx, int by) {
  __shared__ float tile[32][33];
  const int n0 = bx * 32, k0 = by * 32;
  const int tx = threadIdx.x & 31;
  const int ty = threadIdx.x >> 5;
#pragma unroll
  for (int i = 0; i < 32; i += 8)
    tile[ty + i][tx] = W[(size_t)(k0 + ty + i) * N + n0 + tx];
  __syncthreads();
#pragma unroll
  for (int i = 0; i < 32; i += 8)
    WT[(size_t)(n0 + ty + i) * K + k0 + tx] = __float2bfloat16(tile[tx][ty + i]);
}

__global__ __launch_bounds__(256) void prep_kernel(const float* __restrict__ z,
                                                   __hip_bfloat16* __restrict__ a16,
                                                   const float* __restrict__ W1s,
                                                   const float* __restrict__ W1t,
                                                   const float* __restrict__ W2s,
                                                   const float* __restrict__ W2t,
                                                   __hip_bfloat16* __restrict__ w1T,
                                                   __hip_bfloat16* __restrict__ w2sT,
                                                   __hip_bfloat16* __restrict__ w2tT) {
  const int b = blockIdx.x;
  if (b < 4096) {
    const int idx = b * 256 + threadIdx.x;
    const int m  = idx >> 6;
    const int kb = idx & 63;
    const float4* zp = (const float4*)(z + (size_t)m * DDIM + (size_t)kb * 16);
    alignas(16) __hip_bfloat16 t[8];
#pragma unroll
    for (int i = 0; i < 4; ++i) {
      float4 v = zp[i];
      t[2 * i]     = __float2bfloat16(v.x);
      t[2 * i + 1] = __float2bfloat16(v.z);
    }
    *(s8v*)(a16 + (size_t)m * HALF_K + kb * 8) = *(const s8v*)t;
  } else if (b < 6144) {
    const int v = b - 4096;
    transpose_body(W1s, w1T, HALF_K, HID_N, v & 127, v >> 7);
  } else if (b < 8192) {
    const int v = b - 6144;
    transpose_body(W1t, w1T + (size_t)HID_N * HALF_K, HALF_K, HID_N, v & 127, v >> 7);
  } else if (b < 10240) {
    const int v = b - 8192;
    transpose_body(W2s, w2sT, HID_N, HALF_K, v & 15, v >> 4);
  } else {
    const int v = b - 10240;
    transpose_body(W2t, w2tT, HID_N, HALF_K, v & 15, v >> 4);
  }
}

// ---- G1: [SUB x 512] @ [8192 x 512]^T -> H bf16 (relu, bias b1s|b1t) -------
// 256x256 tile, 8 waves, 4-phase, counted vmcnt(4)/tile; one-pass LDS-bounce
// epilogue, cached H stores. Sub-dispatched (4096 rows).
__global__ __launch_bounds__(512, 2)
void gemm1_kernel(const __hip_bfloat16* __restrict__ A,
                  const __hip_bfloat16* __restrict__ BT,
                  const float* __restrict__ b1s, const float* __restrict__ b1t,
                  __hip_bfloat16* __restrict__ Hout) {
  __shared__ alignas(16) char smem[131072];   // 2 x (A 32KB + B 32KB)
  constexpr int NT = HALF_K / 64;             // 8

  const int nwg = gridDim.x;
  const int orig = blockIdx.x;
  const int vid = (orig & 7) * (nwg >> 3) + (orig >> 3);  // XCD-chunked
  const int bx = vid >> 5, by = vid & 31;
  const int m0 = bx * 256, n0 = by * 256;

  const int tid = threadIdx.x;
  const int trow = tid >> 3;
  const int scol = ((tid & 7) * 16) ^ ((trow & 7) << 4);

  const int lane = tid & 63, wid = tid >> 6;
  const int wr = wid >> 2, wc = wid & 3;
  const int lr = lane & 15, lk = lane >> 4;
  const int xo = (lr & 7) << 4;

  int aoff[4][2], boff[2][2];
#pragma unroll
  for (int j = 0; j < 4; ++j)
#pragma unroll
    for (int kk = 0; kk < 2; ++kk)
      aoff[j][kk] = (j * 32 + wr * 16 + lr) * 128 + ((kk * 64 + lk * 16) ^ xo);
#pragma unroll
  for (int nn = 0; nn < 2; ++nn)
#pragma unroll
    for (int kk = 0; kk < 2; ++kk)
      boff[nn][kk] = (nn * 64 + wc * 16 + lr) * 128 + ((kk * 64 + lk * 16) ^ xo);

  f4v acc[8][4] = {};

  auto stage_A = [&](int h, int T) {
#pragma unroll
    for (int l = 0; l < 2; ++l)
      gload16((const char*)A + (size_t)(m0 + h * 128 + l * 64 + trow) * (HALF_K * 2) + (size_t)T * 128 + scol,
              smem + (T & 1) * 65536 + h * 16384 + l * 8192 + tid * 16);
  };
  auto stage_B = [&](int h, int T) {
#pragma unroll
    for (int l = 0; l < 2; ++l)
      gload16((const char*)BT + (size_t)(n0 + h * 128 + l * 64 + trow) * (HALF_K * 2) + (size_t)T * 128 + scol,
              smem + (T & 1) * 65536 + 32768 + h * 16384 + l * 8192 + tid * 16);
  };

  // prologue: tile0 fully + A0/B0 of tile1 (12 gloads); vmcnt(4) -> tile0 done
  stage_A(0, 0); stage_B(0, 0); stage_A(1, 0); stage_B(1, 0);
  stage_A(0, 1); stage_B(0, 1);
  vmw<4>();
  BAR();

  for (int T = 0; T < NT; ++T) {
    const char* bufp = smem + (T & 1) * 65536;
    s8v af[4][2], b0r[2][2], b1r[2][2];

    // q0: read A0 + B0; stage B1(T+1); MFMA acc[0..3][0..1]
#pragma unroll
    for (int j = 0; j < 4; ++j) {
      af[j][0] = *(const s8v*)(bufp + aoff[j][0]);
      af[j][1] = *(const s8v*)(bufp + aoff[j][1]);
    }
#pragma unroll
    for (int nn = 0; nn < 2; ++nn) {
      b0r[nn][0] = *(const s8v*)(bufp + 32768 + boff[nn][0]);
      b0r[nn][1] = *(const s8v*)(bufp + 32768 + boff[nn][1]);
    }
    if (T + 1 < NT) stage_B(1, T + 1);
    BAR(); SCHED0();
    __builtin_amdgcn_s_setprio(1);
#pragma unroll
    for (int j = 0; j < 4; ++j)
#pragma unroll
      for (int nn = 0; nn < 2; ++nn)
#pragma unroll
        for (int kk = 0; kk < 2; ++kk)
          acc[j][nn] = __builtin_amdgcn_mfma_f32_16x16x32_bf16(af[j][kk], b0r[nn][kk], acc[j][nn], 0, 0, 0);
    __builtin_amdgcn_s_setprio(0);
    BAR();

    // q1: read B1; stage A1(T+1); MFMA acc[0..3][2..3]
#pragma unroll
    for (int nn = 0; nn < 2; ++nn) {
      b1r[nn][0] = *(const s8v*)(bufp + 49152 + boff[nn][0]);
      b1r[nn][1] = *(const s8v*)(bufp + 49152 + boff[nn][1]);
    }
    if (T + 1 < NT) stage_A(1, T + 1);
    BAR(); SCHED0();
    __builtin_amdgcn_s_setprio(1);
#pragma unroll
    for (int j = 0; j < 4; ++j)
#pragma unroll
      for (int nn = 0; nn < 2; ++nn)
#pragma unroll
        for (int kk = 0; kk < 2; ++kk)
          acc[j][2 + nn] = __builtin_amdgcn_mfma_f32_16x16x32_bf16(af[j][kk], b1r[nn][kk], acc[j][2 + nn], 0, 0, 0);
    __builtin_amdgcn_s_setprio(0);
    BAR();

    // q2: read A1 (overwrite af); stage A0(T+2); MFMA acc[4..7][0..1] (B0 regs)
#pragma unroll
    for (int j = 0; j < 4; ++j) {
      af[j][0] = *(const s8v*)(bufp + 16384 + aoff[j][0]);
      af[j][1] = *(const s8v*)(bufp + 16384 + aoff[j][1]);
    }
    if (T + 2 < NT) stage_A(0, T + 2);
    BAR(); SCHED0();
    __builtin_amdgcn_s_setprio(1);
#pragma unroll
    for (int j = 0; j < 4; ++j)
#pragma unroll
      for (int nn = 0; nn < 2; ++nn)
#pragma unroll
        for (int kk = 0; kk < 2; ++kk)
          acc[4 + j][nn] = __builtin_amdgcn_mfma_f32_16x16x32_bf16(af[j][kk], b0r[nn][kk], acc[4 + j][nn], 0, 0, 0);
    __builtin_amdgcn_s_setprio(0);
    BAR();

    // q3: no reads; stage B0(T+2); MFMA acc[4..7][2..3] (B1 regs); vmcnt
    if (T + 2 < NT) stage_B(0, T + 2);
    SCHED0();
    __builtin_amdgcn_s_setprio(1);
#pragma unroll
    for (int j = 0; j < 4; ++j)
#pragma unroll
      for (int nn = 0; nn < 2; ++nn)
#pragma unroll
        for (int kk = 0; kk < 2; ++kk)
          acc[4 + j][2 + nn] = __builtin_amdgcn_mfma_f32_16x16x32_bf16(af[j][kk], b1r[nn][kk], acc[4 + j][2 + nn], 0, 0, 0);
    __builtin_amdgcn_s_setprio(0);
    if (T + 2 >= NT) vmw<0>(); else vmw<4>();
    BAR();
  }

  // ---- one-pass epilogue: full 256x256 bf16 image in LDS (128 KB), 2 bars.
  const float* bp = (n0 < HID_N) ? b1s : b1t;
  const int cb0 = n0 & (HID_N - 1);
  float bv[4];
#pragma unroll
  for (int ni = 0; ni < 4; ++ni) bv[ni] = bp[cb0 + ni * 64 + wc * 16 + lr];

#pragma unroll
  for (int mi = 0; mi < 8; ++mi) {
#pragma unroll
    for (int ni = 0; ni < 4; ++ni) {
      const int cb = (ni * 64 + wc * 16 + lr) * 2;
#pragma unroll
      for (int r = 0; r < 4; ++r) {
        const int row = mi * 32 + wr * 16 + lk * 4 + r;
        const int swz = ((row & 7) << 4) ^ (((row >> 3) & 1) << 8);
        float v = fmaxf(acc[mi][ni][r] + bv[ni], 0.0f);
        *(__hip_bfloat16*)(smem + row * 512 + (cb ^ swz)) = __float2bfloat16(v);
      }
    }
  }
  BARS();   // all ds_writes visible before cross-wave readback
#pragma unroll
  for (int i = 0; i < 16; ++i) {
    const int bo = tid * 16 + i * 8192;
    const int row = bo >> 9, cb = bo & 511;
    const int swz = ((row & 7) << 4) ^ (((row >> 3) & 1) << 8);
    s8v v = *(const s8v*)(smem + row * 512 + (cb ^ swz));
    *(s8v*)((char*)Hout + ((size_t)(m0 + row) * LDH + n0) * 2 + cb) = v;   // cached
  }
}

// ---- G2 (best-known): stream-split waves, block 128x128, BK=64,
// 1 barrier/tile, vmcnt(0) covered by ~2000cyc of work. Epilogue s-exchange
// via slds stride 132 (conflict-free).
__global__ __launch_bounds__(512, 2)
void gemm2_kernel(const __hip_bfloat16* __restrict__ H,
                  const __hip_bfloat16* __restrict__ BsT,
                  const __hip_bfloat16* __restrict__ BtT,
                  const float* __restrict__ b2s, const float* __restrict__ b2t,
                  const float* __restrict__ zin, float* __restrict__ zout,
                  float* __restrict__ gpart) {
  __shared__ alignas(16) char smem[131072];   // 2 x (As 16K|At 16K|Bs 16K|Bt 16K)
  constexpr int NT = HID_N / 64;              // 64

  const int nwg = gridDim.x;
  const int orig = blockIdx.x;
  const int vid = (orig & 7) * (nwg >> 3) + (orig >> 3);
  const int rb = vid >> 2, by = vid & 3;
  const int m0 = rb * 128, n0c = by * 128;

  const int tid = threadIdx.x;
  const int trow = tid >> 3;
  const int scol = ((tid & 7) * 16) ^ ((trow & 7) << 4);

  const int lane = tid & 63, wid = tid >> 6;
  const int ws = wid & 1, wc = (wid >> 1) & 1, wr = (wid >> 2) & 1;
  const int lr = lane & 15, lk = lane >> 4;
  const int xo = (lr & 7) << 4;

  const int aBase = ws ? 16384 : 0;        // As | At region
  const int bBase = ws ? 49152 : 32768;    // Bs | Bt region
  int aoff[4][2], boff[4][2];
#pragma unroll
  for (int f = 0; f < 4; ++f)
#pragma unroll
    for (int kk = 0; kk < 2; ++kk) {
      aoff[f][kk] = aBase + (wr * 64 + f * 16 + lr) * 128 + ((kk * 64 + lk * 16) ^ xo);
      boff[f][kk] = bBase + (wc * 64 + f * 16 + lr) * 128 + ((kk * 64 + lk * 16) ^ xo);
    }

  f4v acc[4][4] = {};

  auto stage_all = [&](int T) {
    char* dst = smem + (T & 1) * 65536;
    const size_t tcol = (size_t)T * 128 + scol;
#pragma unroll
    for (int l = 0; l < 2; ++l)   // As (H s-half)
      gload16((const char*)H + (size_t)(m0 + l * 64 + trow) * (LDH * 2) + tcol,
              dst + l * 8192 + tid * 16);
#pragma unroll
    for (int l = 0; l < 2; ++l)   // At (H t-half, +8192 B)
      gload16((const char*)H + (size_t)(m0 + l * 64 + trow) * (LDH * 2) + 8192 + tcol,
              dst + 16384 + l * 8192 + tid * 16);
#pragma unroll
    for (int l = 0; l < 2; ++l)   // Bs
      gload16((const char*)BsT + (size_t)(n0c + l * 64 + trow) * (HID_N * 2) + tcol,
              dst + 32768 + l * 8192 + tid * 16);
#pragma unroll
    for (int l = 0; l < 2; ++l)   // Bt
      gload16((const char*)BtT + (size_t)(n0c + l * 64 + trow) * (HID_N * 2) + tcol,
              dst + 49152 + l * 8192 + tid * 16);
  };

  stage_all(0);
  vmw<0>();
  BAR();

  for (int T = 0; T < NT; ++T) {
    const char* bufp = smem + (T & 1) * 65536;
    s8v af[4], bf[4];

    // P0: kk=0 frags; issue ALL of T+1 (other buffer - its readers done at T-1)
#pragma unroll
    for (int f = 0; f < 4; ++f) af[f] = *(const s8v*)(bufp + aoff[f][0]);
#pragma unroll
    for (int f = 0; f < 4; ++f) bf[f] = *(const s8v*)(bufp + boff[f][0]);
    if (T + 1 < NT) stage_all(T + 1);
    __builtin_amdgcn_s_setprio(1);
#pragma unroll
    for (int fm = 0; fm < 4; ++fm)
#pragma unroll
      for (int fn = 0; fn < 4; ++fn)
        acc[fm][fn] = __builtin_amdgcn_mfma_f32_16x16x32_bf16(af[fm], bf[fn], acc[fm][fn], 0, 0, 0);
    __builtin_amdgcn_s_setprio(0);

    // P1: kk=1 frags
#pragma unroll
    for (int f = 0; f < 4; ++f) af[f] = *(const s8v*)(bufp + aoff[f][1]);
#pragma unroll
    for (int f = 0; f < 4; ++f) bf[f] = *(const s8v*)(bufp + boff[f][1]);
    __builtin_amdgcn_s_setprio(1);
#pragma unroll
    for (int fm = 0; fm < 4; ++fm)
#pragma unroll
      for (int fn = 0; fn < 4; ++fn)
        acc[fm][fn] = __builtin_amdgcn_mfma_f32_16x16x32_bf16(af[fm], bf[fn], acc[fm][fn], 0, 0, 0);
    __builtin_amdgcn_s_setprio(0);

    if (T + 1 < NT) vmw<0>();   // T+1 landed (issued ~2000 cyc ago)
    BAR();                      // all waves done with buf; next buf ready
  }

  // ---- epilogue: s-waves park s+bias in slds[128][132] f32 (conflict-free);
  // t-waves fuse zout (nt) + logdet.
  const float* bp2 = ws ? b2t : b2s;
  float bv[4];
#pragma unroll
  for (int fn = 0; fn < 4; ++fn) bv[fn] = bp2[n0c + wc * 64 + fn * 16 + lr];

  float* slds = (float*)smem;   // [128][132] f32 = 67.6 KB
  if (ws == 0) {
#pragma unroll
    for (int fm = 0; fm < 4; ++fm)
#pragma unroll
      for (int fn = 0; fn < 4; ++fn)
#pragma unroll
        for (int r = 0; r < 4; ++r) {
          const int row = wr * 64 + fm * 16 + lk * 4 + r;
          const int col = wc * 64 + fn * 16 + lr;
          slds[row * 132 + col] = acc[fm][fn][r] + bv[fn];
        }
  }
  BARS();
  if (ws == 1) {
    float pl[4][4] = {};
#pragma unroll
    for (int fm = 0; fm < 4; ++fm) {
#pragma unroll
      for (int fn = 0; fn < 4; ++fn) {
#pragma unroll
        for (int r = 0; r < 4; ++r) {
          const int row = wr * 64 + fm * 16 + lk * 4 + r;
          const int col = wc * 64 + fn * 16 + lr;
          const int rr = m0 + row;
          const float sv = slds[row * 132 + col];
          const float tv = acc[fm][fn][r] + bv[fn];
          pl[fm][r] += sv;
          const size_t base = (size_t)rr * DDIM + 2 * (size_t)(n0c + col);
          float2 zv = *(const float2*)(zin + base);
          f2v o;
          o.x = zv.x;
          o.y = zv.y * __expf(sv) + tv;
          __builtin_nontemporal_store(o, (f2v*)(zout + base));
        }
      }
    }
    // reduce over the 16 lr-lanes (rows depend only on lk)
#pragma unroll
    for (int m = 1; m < 16; m <<= 1)
#pragma unroll
      for (int fm = 0; fm < 4; ++fm)
#pragma unroll
        for (int r = 0; r < 4; ++r)
          pl[fm][r] += __shfl_xor(pl[fm][r], m, 64);
    if (lr == 0) {
#pragma unroll
      for (int fm = 0; fm < 4; ++fm)
#pragma unroll
        for (int r = 0; r < 4; ++r) {
          const int rr = m0 + wr * 64 + fm * 16 + lk * 4 + r;
          gpart[(size_t)rr * 8 + by * 2 + wc] = pl[fm][r];
        }
    }
  }
}

// ---- ld[row] = sum of 8 partials (fixed order) -----------------------------
__global__ __launch_bounds__(256) void ld_reduce_kernel(const float* __restrict__ gpart,
                                                        float* __restrict__ ld) {
  const int r = blockIdx.x * 256 + threadIdx.x;
  const float4* g = (const float4*)(gpart + (size_t)r * 8);
  float4 v0 = g[0], v1 = g[1];
  ld[r] = ((v0.x + v0.y) + (v0.z + v0.w)) + ((v1.x + v1.y) + (v1.z + v1.w));
}

extern "C" void kernel_launch(void* const* d_in, const int* in_sizes, int n_in,
                              void* d_out, int out_size, void* d_ws, size_t ws_size,
                              hipStream_t stream) {
  const float* z   = (const float*)d_in[0];
  const float* W1s = (const float*)d_in[1];
  const float* b1s = (const float*)d_in[2];
  const float* W2s = (const float*)d_in[3];
  const float* b2s = (const float*)d_in[4];
  const float* W1t = (const float*)d_in[5];
  const float* b1t = (const float*)d_in[6];
  const float* W2t = (const float*)d_in[7];
  const float* b2t = (const float*)d_in[8];
  float* zout = (float*)d_out;
  float* ld   = zout + (size_t)BROWS * DDIM;

  char* ws = (char*)d_ws;
  __hip_bfloat16* a16    = (__hip_bfloat16*)ws;                    // 16 MB
  __hip_bfloat16* w1catT = (__hip_bfloat16*)(ws + 16777216);       // 8 MB
  __hip_bfloat16* w2sT   = (__hip_bfloat16*)(ws + 25165824);       // 4 MB
  __hip_bfloat16* w2tT   = (__hip_bfloat16*)(ws + 29360128);       // 4 MB
  float*          gpart  = (float*)(ws + 33554432);                // 512 KB
  char*           hbase  = ws + 34078720;

  // CH=8192 (gemm2 grid 256 = full machine); fall back if ws is small.
  int CH = 2048;
  for (int c = 8192; c >= 2048; c >>= 1) {
    if (34078720ull + (size_t)c * 16384ull <= ws_size) { CH = c; break; }
  }
  __hip_bfloat16* H = (__hip_bfloat16*)hbase;   // CH x 8192 bf16

  // single merged prep dispatch (cast_a + 4 transposes)
  prep_kernel<<<12288, 256, 0, stream>>>(z, a16, W1s, W1t, W2s, W2t,
                                         w1catT, w2sT, w2tT);

  const int SUB = (CH >= 4096) ? 4096 : CH;   // gemm1 sub-dispatch rows
  for (int mb = 0; mb < BROWS; mb += CH) {
    for (int sub = 0; sub < CH; sub += SUB) {
      gemm1_kernel<<<(SUB / 256) * 32, 512, 0, stream>>>(
          a16 + (size_t)(mb + sub) * HALF_K, w1catT, b1s, b1t,
          H + (size_t)sub * LDH);
    }
    gemm2_kernel<<<(CH / 128) * 4, 512, 0, stream>>>(
        H, w2sT, w2tT, b2s, b2t,
        z + (size_t)mb * DDIM, zout + (size_t)mb * DDIM, gpart + (size_t)mb * 8);
  }
  ld_reduce_kernel<<<BROWS / 256, 256, 0, stream>>>(gpart, ld);
}